// Round 2
// baseline (391.980 us; speedup 1.0000x reference)
//
#include <hip/hip_runtime.h>
#include <hip/hip_fp16.h>
#include <math.h>

#define T_ 1024
#define B_ 512
#define I_ 128
#define H_ 256
#define K_ 384   /* I_ + H_ */
#define KP_ 192  /* k-pairs */

typedef _Float16 h2_t __attribute__((ext_vector_type(2)));

__device__ __forceinline__ float fsigmoid(float x) {
  return 1.0f / (1.0f + __expf(-x));
}
__device__ __forceinline__ float ftanh(float x) {
  float ax = fabsf(x);
  float e = __expf(-2.0f * ax);  // in (0,1], no overflow
  float t = (1.0f - e) / (1.0f + e);
  return copysignf(t, x);
}
// acc += dot2(fp16 pair w, fp16 pair v)  -> v_dot2_f32_f16
__device__ __forceinline__ void dot2(float& acc, unsigned int w, unsigned int v) {
  acc = __builtin_amdgcn_fdot2(__builtin_bit_cast(h2_t, w),
                               __builtin_bit_cast(h2_t, v), acc, false);
}

// ---------------------------------------------------------------------------
// Pack fused fp32 weights [W_ih | W_hh] into fp16 gate-quads:
//   Whq[(kp*H_ + j)*8 + g*2 + d] = (half) W_fused[g*H_ + j][2kp + d]
// One uint4 = 4 gates x 2 k's for unit j, k-pair kp.
// Also zeroes the per-batch start table (workspace is poisoned each launch).
// ---------------------------------------------------------------------------
__global__ void prep_kernel(const float* __restrict__ W_ih,
                            const float* __restrict__ W_hh,
                            const float* __restrict__ b_ih,
                            const float* __restrict__ b_hh,
                            __half* __restrict__ Whq,
                            float4* __restrict__ biasq,
                            int* __restrict__ sstart) {
  const int j = (int)threadIdx.x;   // 0..255
  const int kp = (int)blockIdx.x;   // 0..191
  const int k0 = 2 * kp, k1 = 2 * kp + 1;
  __half* dst = Whq + ((size_t)(kp * H_ + j)) * 8;
#pragma unroll
  for (int g = 0; g < 4; ++g) {
    const int row = g * H_ + j;
    float w0, w1;
    if (k0 < I_) {
      w0 = W_ih[row * I_ + k0];
      w1 = W_ih[row * I_ + k1];
    } else {
      w0 = W_hh[row * H_ + (k0 - I_)];
      w1 = W_hh[row * H_ + (k1 - I_)];
    }
    dst[g * 2 + 0] = __float2half(w0);
    dst[g * 2 + 1] = __float2half(w1);
  }
  if (kp == 0) {
    biasq[j] = make_float4(b_ih[j] + b_hh[j],
                           b_ih[H_ + j] + b_hh[H_ + j],
                           b_ih[2 * H_ + j] + b_hh[2 * H_ + j],
                           b_ih[3 * H_ + j] + b_hh[3 * H_ + j]);
    sstart[j] = 0;
    sstart[H_ + j] = 0;
  }
}

// ---------------------------------------------------------------------------
// Mask scan (coalesced): the carry is (m*h, m*c) with m in {0,1}; when m==0
// the state is EXACTLY zeroed, so batch b's result depends only on steps
// after the last reset:
//   sstart[b] = 1 + max{ t <= T-2 : x[t,b,I-1] <= 0 }   (0 if none).
// Lanes run over BATCH (512 B stride -> each wave spans a contiguous 32 KB
// region, streaming-friendly), each thread covers 4 t's, one atomicMax per
// thread into sstart[b].  Grid 128 x 1024 covers t = 0..1023 (t<=1022 used).
// ---------------------------------------------------------------------------
__global__ __launch_bounds__(1024) void scan_kernel(
    const float* __restrict__ x,  // [T,B,I]
    int* __restrict__ sstart) {   // [B_]
  const int tid = (int)threadIdx.x;
  const int b = tid & (B_ - 1);
  const int half = tid >> 9;  // 0,1
  const int t0 = (int)blockIdx.x * 8 + half * 4;
  int best = 0;
#pragma unroll
  for (int it = 0; it < 4; ++it) {
    const int t = t0 + it;
    if (t <= T_ - 2) {
      const float xv = x[((long)t * B_ + b) * I_ + (I_ - 1)];
      if (xv <= 0.0f) best = t + 1;  // increasing t, overwrite == max
    }
  }
  if (best > 0) atomicMax(sstart + b, best);
}

// ---------------------------------------------------------------------------
// Main kernel: grid 256 x 1024 threads. Block handles batches {2b, 2b+1},
// starting at ts = min(sstart[2b], sstart[2b+1]) with zero state (exact:
// each batch's own m==0 step re-zeroes its state at the right time).
//
// Thread (kq = tid>>8 in 0..3, j = tid&255):
//   dot phase : v_dot2_f32_f16 partial gate sums for BOTH batches over
//               k-quarter kq (weights loaded once, fp16, no duplication)
//   act phase : threads kq<2 finalize batch kq, unit j after 4-way LDS
//               partial exchange.
// ---------------------------------------------------------------------------
__global__ __launch_bounds__(1024) void lstm_kernel(
    const float* __restrict__ x,      // [T,B,I] fp32
    const uint4* __restrict__ W4,     // [KP_*H_] packed fp16 gate-quads
    const float4* __restrict__ biasq, // [H_]
    const int* __restrict__ sstart,   // [B_] per-batch start step
    const float* __restrict__ W_out,  // [H_]
    const float* __restrict__ b_out,  // [1]
    float* __restrict__ out) {        // [B_]
  __shared__ __align__(16) __half v[2][K_];        // [x_t ; h] fp16 per batch
  __shared__ __align__(16) float4 part[4][2][H_];  // [kq][batch][j]
  __shared__ float msk[2];
  __shared__ float red[8];
  const int tid = (int)threadIdx.x;
  const int kq = tid >> 8;       // k-quarter (dot) / batch (act, if <2)
  const int j = tid & (H_ - 1);  // hidden unit
  const int b0 = (int)blockIdx.x * 2;

  const float4 bias = biasq[j];
  const int ts = min(sstart[b0], sstart[b0 + 1]);

  // init: h0 = 0 (fp16), stage x for t=ts, mask for t=ts
  if (kq < 2) v[kq][I_ + j] = __float2half(0.0f);
  if (tid < 2 * I_) {
    const int sb = tid >> 7, ii = tid & (I_ - 1);
    const float xv = x[((long)ts * B_ + (b0 + sb)) * I_ + ii];
    v[sb][ii] = __float2half(xv);
    if (ii == I_ - 1) msk[sb] = (xv > 0.0f) ? 1.0f : 0.0f;
  }

  float c = 0.0f, lasth = 0.0f;
  const uint4* __restrict__ wbase = W4 + (size_t)(kq * (KP_ / 4)) * H_ + j;
  const uint4* __restrict__ v0q = (const uint4*)(&v[0][kq * (K_ / 4)]);
  const uint4* __restrict__ v1q = (const uint4*)(&v[1][kq * (K_ / 4)]);

  for (int t = ts; t < T_; ++t) {
    __syncthreads();  // (A) x_t, h_{t-1}, msk visible
    float m = 0.0f;
    if (kq < 2) m = msk[kq];  // read BEFORE next staging overwrites it

    float4 acc0 = make_float4(0.f, 0.f, 0.f, 0.f);
    float4 acc1 = make_float4(0.f, 0.f, 0.f, 0.f);
    const uint4* wp = wbase;
#pragma unroll 4
    for (int i = 0; i < 12; ++i) {  // 8 k's per iter
      const uint4 va = v0q[i];      // 8 fp16 of [x;h], batch 0 (LDS broadcast)
      const uint4 vb = v1q[i];      // batch 1
      const uint4 w0 = wp[0];       // gate-quad, k-pair 4i+0
      const uint4 w1 = wp[H_];      // 4i+1
      const uint4 w2 = wp[2 * H_];  // 4i+2
      const uint4 w3 = wp[3 * H_];  // 4i+3
      wp += 4 * H_;
      dot2(acc0.x, w0.x, va.x); dot2(acc0.y, w0.y, va.x);
      dot2(acc0.z, w0.z, va.x); dot2(acc0.w, w0.w, va.x);
      dot2(acc1.x, w0.x, vb.x); dot2(acc1.y, w0.y, vb.x);
      dot2(acc1.z, w0.z, vb.x); dot2(acc1.w, w0.w, vb.x);
      dot2(acc0.x, w1.x, va.y); dot2(acc0.y, w1.y, va.y);
      dot2(acc0.z, w1.z, va.y); dot2(acc0.w, w1.w, va.y);
      dot2(acc1.x, w1.x, vb.y); dot2(acc1.y, w1.y, vb.y);
      dot2(acc1.z, w1.z, vb.y); dot2(acc1.w, w1.w, vb.y);
      dot2(acc0.x, w2.x, va.z); dot2(acc0.y, w2.y, va.z);
      dot2(acc0.z, w2.z, va.z); dot2(acc0.w, w2.w, va.z);
      dot2(acc1.x, w2.x, vb.z); dot2(acc1.y, w2.y, vb.z);
      dot2(acc1.z, w2.z, vb.z); dot2(acc1.w, w2.w, vb.z);
      dot2(acc0.x, w3.x, va.w); dot2(acc0.y, w3.y, va.w);
      dot2(acc0.z, w3.z, va.w); dot2(acc0.w, w3.w, va.w);
      dot2(acc1.x, w3.x, vb.w); dot2(acc1.y, w3.y, vb.w);
      dot2(acc1.z, w3.z, vb.w); dot2(acc1.w, w3.w, vb.w);
    }
    part[kq][0][j] = acc0;
    part[kq][1][j] = acc1;
    __syncthreads();  // (B) partials visible; all v/msk reads done

    if (kq < 2) {  // act phase: batch kq, unit j
      const float4 p0 = part[0][kq][j];
      const float4 p1 = part[1][kq][j];
      const float4 p2 = part[2][kq][j];
      const float4 p3 = part[3][kq][j];
      const float gi = fsigmoid(p0.x + p1.x + p2.x + p3.x + bias.x);
      const float gf = fsigmoid(p0.y + p1.y + p2.y + p3.y + bias.y);
      const float gg = ftanh(p0.z + p1.z + p2.z + p3.z + bias.z);
      const float go = fsigmoid(p0.w + p1.w + p2.w + p3.w + bias.w);
      const float cn = gf * c + gi * gg;
      const float hn = go * ftanh(cn);
      if (t == T_ - 1) lasth = hn;  // hs[-1] is the UNMASKED h_new
      c = m * cn;
      v[kq][I_ + j] = __float2half(m * hn);  // h carry (masked)
    }
    if (t + 1 < T_ && tid < 2 * I_) {  // stage x_{t+1} + its mask
      const int sb = tid >> 7, ii = tid & (I_ - 1);
      const float xv = x[((long)(t + 1) * B_ + (b0 + sb)) * I_ + ii];
      v[sb][ii] = __float2half(xv);
      if (ii == I_ - 1) msk[sb] = (xv > 0.0f) ? 1.0f : 0.0f;
    }
  }

  // likelihood[b0+bb] = sum_j W_out[j] * lasth + b_out   (threads kq<2 only)
  float p = (kq < 2) ? W_out[j] * lasth : 0.0f;
#pragma unroll
  for (int off = 32; off > 0; off >>= 1) p += __shfl_down(p, off, 64);
  const int wave = tid >> 6;
  if (wave < 8 && (tid & 63) == 0) red[wave] = p;
  __syncthreads();
  if (tid == 0)   out[b0]     = red[0] + red[1] + red[2] + red[3] + b_out[0];
  if (tid == 256) out[b0 + 1] = red[4] + red[5] + red[6] + red[7] + b_out[0];
}

extern "C" void kernel_launch(void* const* d_in, const int* in_sizes, int n_in,
                              void* d_out, int out_size, void* d_ws, size_t ws_size,
                              hipStream_t stream) {
  (void)in_sizes; (void)n_in; (void)out_size; (void)ws_size;
  const float* x     = (const float*)d_in[0];  // [T,B,I]
  const float* W_ih  = (const float*)d_in[1];  // [4H,I]
  const float* W_hh  = (const float*)d_in[2];  // [4H,H]
  const float* b_ih  = (const float*)d_in[3];  // [4H]
  const float* b_hh  = (const float*)d_in[4];  // [4H]
  const float* W_out = (const float*)d_in[5];  // [1,H]
  const float* b_out = (const float*)d_in[6];  // [1]
  float* out = (float*)d_out;                  // [B]

  char* ws = (char*)d_ws;
  __half* Whq   = (__half*)ws;                       // 786,432 B
  float4* biasq = (float4*)(ws + (size_t)KP_ * H_ * 8 * sizeof(__half));
  int*    sst   = (int*)((char*)biasq + (size_t)H_ * sizeof(float4));

  hipLaunchKernelGGL(prep_kernel, dim3(KP_), dim3(H_), 0, stream,
                     W_ih, W_hh, b_ih, b_hh, Whq, biasq, sst);
  hipLaunchKernelGGL(scan_kernel, dim3(T_ / 8), dim3(1024), 0, stream,
                     x, sst);
  hipLaunchKernelGGL(lstm_kernel, dim3(B_ / 2), dim3(1024), 0, stream,
                     x, (const uint4*)Whq, biasq, sst, W_out, b_out, out);
}

// Round 4
// 387.663 us; speedup vs baseline: 1.0111x; 1.0111x over previous
//
#include <hip/hip_runtime.h>
#include <hip/hip_fp16.h>
#include <math.h>

#define T_ 1024
#define B_ 512
#define I_ 128
#define H_ 256
#define K_ 384   /* I_ + H_ */
#define KP_ 192  /* k-pairs */
#define REG_N 8  /* weight quads cached in registers (n = 0..7)   */
#define LDS_N 7  /* weight quads cached in LDS       (n = 8..14)  */
#define NWIN 64  /* scan windows of 16 timesteps */

typedef _Float16 h2_t __attribute__((ext_vector_type(2)));

__device__ __forceinline__ float fsigmoid(float x) {
  return 1.0f / (1.0f + __expf(-x));
}
__device__ __forceinline__ float ftanh(float x) {
  float ax = fabsf(x);
  float e = __expf(-2.0f * ax);  // in (0,1], no overflow
  float t = (1.0f - e) / (1.0f + e);
  return copysignf(t, x);
}
// acc += dot2(fp16 pair w, fp16 pair v)  -> v_dot2_f32_f16
__device__ __forceinline__ void dot2(float& acc, unsigned int w, unsigned int v) {
  acc = __builtin_amdgcn_fdot2(__builtin_bit_cast(h2_t, w),
                               __builtin_bit_cast(h2_t, v), acc, false);
}

// 8 dot2's: one gate-quad w against component C of va (batch0) / vb (batch1)
#define ACC8(W, VA, VB, C)                                      \
  dot2(acc0.x, (W).x, (VA).C); dot2(acc0.y, (W).y, (VA).C);     \
  dot2(acc0.z, (W).z, (VA).C); dot2(acc0.w, (W).w, (VA).C);     \
  dot2(acc1.x, (W).x, (VB).C); dot2(acc1.y, (W).y, (VB).C);     \
  dot2(acc1.z, (W).z, (VB).C); dot2(acc1.w, (W).w, (VB).C);

// ---------------------------------------------------------------------------
// Fused prep + mask-scan kernel, grid 112 x 1024.
//  blocks 0..47  : pack fused fp32 weights [W_ih | W_hh] into fp16 gate-quads
//                  Whq[(kp*H_ + j)*8 + g*2 + d] = (half) W[g*H_+j][2kp+d],
//                  kp = bx*4 + (tid>>8), j = tid&255.  Block 0 also builds
//                  the fused bias.
//  blocks 48..111: mask scan.  The carry is (m*h, m*c), m in {0,1}; m==0
//                  EXACTLY zeroes the state, so batch b depends only on
//                  steps after its last reset
//                    s_b = 1 + max{ t <= T-2 : x[t,b,I-1] <= 0 }  (0 if none).
//                  Window win = bx-48 covers t in [16win, 16win+16); lanes
//                  run over batch (coalesced spread); per-window max stored
//                  to partial[win][b] with plain stores (NO atomics).
// ---------------------------------------------------------------------------
__global__ __launch_bounds__(1024) void prep_scan_kernel(
    const float* __restrict__ W_ih,
    const float* __restrict__ W_hh,
    const float* __restrict__ b_ih,
    const float* __restrict__ b_hh,
    const float* __restrict__ x,
    __half* __restrict__ Whq,
    float4* __restrict__ biasq,
    int* __restrict__ partial) {  // [NWIN][B_]
  __shared__ int smax[2][B_];
  const int tid = (int)threadIdx.x;
  const int bx = (int)blockIdx.x;

  if (bx < 48) {  // ---- prep ----
    const int kp = bx * 4 + (tid >> 8);
    const int j = tid & (H_ - 1);
    const int k0 = 2 * kp, k1 = 2 * kp + 1;
    __half* dst = Whq + ((size_t)(kp * H_ + j)) * 8;
#pragma unroll
    for (int g = 0; g < 4; ++g) {
      const int row = g * H_ + j;
      float w0, w1;
      if (k0 < I_) {
        w0 = W_ih[row * I_ + k0];
        w1 = W_ih[row * I_ + k1];
      } else {
        w0 = W_hh[row * H_ + (k0 - I_)];
        w1 = W_hh[row * H_ + (k1 - I_)];
      }
      dst[g * 2 + 0] = __float2half(w0);
      dst[g * 2 + 1] = __float2half(w1);
    }
    if (bx == 0 && tid < H_) {
      const int jj = tid;
      biasq[jj] = make_float4(b_ih[jj] + b_hh[jj],
                              b_ih[H_ + jj] + b_hh[H_ + jj],
                              b_ih[2 * H_ + jj] + b_hh[2 * H_ + jj],
                              b_ih[3 * H_ + jj] + b_hh[3 * H_ + jj]);
    }
  } else {  // ---- scan ----
    const int win = bx - 48;
    const int b = tid & (B_ - 1);
    const int half = tid >> 9;  // 0,1
    int best = 0;
    const float* __restrict__ px = x + (long)b * I_ + (I_ - 1);
#pragma unroll
    for (int it = 0; it < 8; ++it) {
      const int t = win * 16 + half * 8 + it;
      if (t <= T_ - 2) {
        const float xv = px[(long)t * ((long)B_ * I_)];
        if (xv <= 0.0f) best = t + 1;  // increasing t: overwrite == max
      }
    }
    smax[half][b] = best;
    __syncthreads();
    if (tid < B_) partial[win * B_ + tid] = max(smax[0][tid], smax[1][tid]);
  }
}

// ---------------------------------------------------------------------------
// Main kernel: grid 256 x 1024 (1 block/CU, 16 waves). Block handles batches
// {2b, 2b+1}, starting at ts = min over the pair of per-batch start steps
// (reduced from partial[] in wave 0) with zero state -- exact, each batch's
// own m==0 step re-zeroes its state at the right time.
//
// Weight residency: of each thread's 48 gate-quads, n=0..7 live in VGPRs and
// n=8..14 in LDS across ALL steps (the per-CU L2 stream drops 786->540 KB /
// step; grid==256 means 1 block/CU so the extra LDS/VGPRs cost nothing).
// First step (t==ts): h is exactly 0 for both batches, so streamed quads
// with k>=I_ (the W_hh part) are skipped -- their contribution is exactly 0.
// nskip = count of STREAMED quads to keep on the first step:
//   kq0 -> 48 (all 48 of its quads are x-quads, k in [0,96))
//   kq1 -> 16 (only n=15, k=126..127, is an x-quad among the streamed ones)
//   kq2/3 -> 0 (all streamed quads are W_hh)
// (r3 BUG: max(0, 64-kq*48) gave 64 for kq0, skipping its streamed x-quads.)
// ---------------------------------------------------------------------------
__global__ __launch_bounds__(1024) void lstm_kernel(
    const float* __restrict__ x,       // [T,B,I] fp32
    const uint4* __restrict__ W4,      // [KP_*H_] packed fp16 gate-quads
    const float4* __restrict__ biasq,  // [H_]
    const int* __restrict__ partial,   // [NWIN][B_] scan partial maxima
    const float* __restrict__ W_out,   // [H_]
    const float* __restrict__ b_out,   // [1]
    float* __restrict__ out) {         // [B_]
  __shared__ __align__(16) __half v[2][K_];        // [x_t ; h] fp16 per batch
  __shared__ __align__(16) float4 part[4][2][H_];  // [kq][batch][j]
  __shared__ __align__(16) uint4 lw[LDS_N][1024];  // LDS-resident weight quads
  __shared__ float msk[2];
  __shared__ float red[8];
  __shared__ int sh_ts;
  const int tid = (int)threadIdx.x;
  const int kq = tid >> 8;       // k-quarter (dot) / batch (act, if <2)
  const int j = tid & (H_ - 1);  // hidden unit
  const int b0 = (int)blockIdx.x * 2;

  const float4 bias = biasq[j];
  const uint4* __restrict__ wbase = W4 + (size_t)(kq * (KP_ / 4)) * H_ + j;

  // prefetch persistent weight quads (registers + LDS), issued first so the
  // loads overlap the partial-reduce below
  uint4 rw[REG_N];
#pragma unroll
  for (int n = 0; n < REG_N; ++n) rw[n] = wbase[(size_t)n * H_];
#pragma unroll
  for (int m = 0; m < LDS_N; ++m) lw[m][tid] = wbase[(size_t)(REG_N + m) * H_];

  // reduce the pair's start step over the NWIN scan windows (wave 0)
  if (tid < 64) {
    const int2 pv = *(const int2*)(partial + tid * B_ + b0);  // b0 even -> 8B aligned
    int s0 = pv.x, s1 = pv.y;
#pragma unroll
    for (int off = 32; off > 0; off >>= 1) {
      s0 = max(s0, __shfl_down(s0, off, 64));
      s1 = max(s1, __shfl_down(s1, off, 64));
    }
    if (tid == 0) sh_ts = min(s0, s1);
  }
  if (kq < 2) v[kq][I_ + j] = __float2half(0.0f);  // h0 = 0
  __syncthreads();  // publish sh_ts (and h-zero)
  const int ts = sh_ts;

  // stage x for t=ts + its mask
  if (tid < 2 * I_) {
    const int sb = tid >> 7, ii = tid & (I_ - 1);
    const float xv = x[((long)ts * B_ + (b0 + sb)) * I_ + ii];
    v[sb][ii] = __float2half(xv);
    if (ii == I_ - 1) msk[sb] = (xv > 0.0f) ? 1.0f : 0.0f;
  }

  float c = 0.0f, lasth = 0.0f;
  const uint4* __restrict__ v0q = (const uint4*)(&v[0][kq * (K_ / 4)]);
  const uint4* __restrict__ v1q = (const uint4*)(&v[1][kq * (K_ / 4)]);

  for (int t = ts; t < T_; ++t) {
    __syncthreads();  // (A) x_t, h_{t-1}, msk, lw visible
    float m = 0.0f;
    if (kq < 2) m = msk[kq];  // read BEFORE next staging overwrites it
    const int nskip = (t != ts) ? 48 : ((kq == 0) ? 48 : (kq == 1) ? 16 : 0);

    float4 acc0 = make_float4(0.f, 0.f, 0.f, 0.f);
    float4 acc1 = make_float4(0.f, 0.f, 0.f, 0.f);
    {  // n = 0..7 : register-resident
      const uint4 va = v0q[0], vb = v1q[0];
      ACC8(rw[0], va, vb, x); ACC8(rw[1], va, vb, y);
      ACC8(rw[2], va, vb, z); ACC8(rw[3], va, vb, w);
    }
    {
      const uint4 va = v0q[1], vb = v1q[1];
      ACC8(rw[4], va, vb, x); ACC8(rw[5], va, vb, y);
      ACC8(rw[6], va, vb, z); ACC8(rw[7], va, vb, w);
    }
    {  // n = 8..11 : LDS-resident
      const uint4 va = v0q[2], vb = v1q[2];
      const uint4 w0 = lw[0][tid], w1 = lw[1][tid];
      const uint4 w2 = lw[2][tid], w3 = lw[3][tid];
      ACC8(w0, va, vb, x); ACC8(w1, va, vb, y);
      ACC8(w2, va, vb, z); ACC8(w3, va, vb, w);
    }
    {  // n = 12..14 : LDS-resident
      const uint4 va = v0q[3], vb = v1q[3];
      const uint4 w0 = lw[4][tid], w1 = lw[5][tid], w2 = lw[6][tid];
      ACC8(w0, va, vb, x); ACC8(w1, va, vb, y); ACC8(w2, va, vb, z);
    }
    if (nskip == 48) {  // hot path: stream n = 15..47, branch-free
      {
        const uint4 va = v0q[3], vb = v1q[3];
        const uint4 w3 = wbase[(size_t)15 * H_];
        ACC8(w3, va, vb, w);
      }
#pragma unroll 2
      for (int i = 4; i < 12; ++i) {
        const uint4 va = v0q[i], vb = v1q[i];
        const uint4* wp = wbase + (size_t)(4 * i) * H_;
        { const uint4 w = wp[0];      ACC8(w, va, vb, x); }
        { const uint4 w = wp[H_];     ACC8(w, va, vb, y); }
        { const uint4 w = wp[2 * H_]; ACC8(w, va, vb, z); }
        { const uint4 w = wp[3 * H_]; ACC8(w, va, vb, w); }
      }
    } else if (nskip == 16) {  // first step, kq==1: only n=15 is an x-quad
      const uint4 va = v0q[3], vb = v1q[3];
      const uint4 w3 = wbase[(size_t)15 * H_];
      ACC8(w3, va, vb, w);
    }  // first step, kq>=2: all streamed quads are W_hh -> exactly 0, skip
    part[kq][0][j] = acc0;
    part[kq][1][j] = acc1;
    __syncthreads();  // (B) partials visible; all v/msk reads done

    if (kq < 2) {  // act phase: batch kq, unit j
      const float4 p0 = part[0][kq][j];
      const float4 p1 = part[1][kq][j];
      const float4 p2 = part[2][kq][j];
      const float4 p3 = part[3][kq][j];
      const float gi = fsigmoid(p0.x + p1.x + p2.x + p3.x + bias.x);
      const float gf = fsigmoid(p0.y + p1.y + p2.y + p3.y + bias.y);
      const float gg = ftanh(p0.z + p1.z + p2.z + p3.z + bias.z);
      const float go = fsigmoid(p0.w + p1.w + p2.w + p3.w + bias.w);
      const float cn = gf * c + gi * gg;
      const float hn = go * ftanh(cn);
      if (t == T_ - 1) lasth = hn;  // hs[-1] is the UNMASKED h_new
      c = m * cn;
      v[kq][I_ + j] = __float2half(m * hn);  // h carry (masked)
    }
    if (t + 1 < T_ && tid < 2 * I_) {  // stage x_{t+1} + its mask
      const int sb = tid >> 7, ii = tid & (I_ - 1);
      const float xv = x[((long)(t + 1) * B_ + (b0 + sb)) * I_ + ii];
      v[sb][ii] = __float2half(xv);
      if (ii == I_ - 1) msk[sb] = (xv > 0.0f) ? 1.0f : 0.0f;
    }
  }

  // likelihood[b0+bb] = sum_j W_out[j] * lasth + b_out   (threads kq<2 only)
  float p = (kq < 2) ? W_out[j] * lasth : 0.0f;
#pragma unroll
  for (int off = 32; off > 0; off >>= 1) p += __shfl_down(p, off, 64);
  const int wave = tid >> 6;
  if (wave < 8 && (tid & 63) == 0) red[wave] = p;
  __syncthreads();
  if (tid == 0)   out[b0]     = red[0] + red[1] + red[2] + red[3] + b_out[0];
  if (tid == 256) out[b0 + 1] = red[4] + red[5] + red[6] + red[7] + b_out[0];
}

extern "C" void kernel_launch(void* const* d_in, const int* in_sizes, int n_in,
                              void* d_out, int out_size, void* d_ws, size_t ws_size,
                              hipStream_t stream) {
  (void)in_sizes; (void)n_in; (void)out_size; (void)ws_size;
  const float* x     = (const float*)d_in[0];  // [T,B,I]
  const float* W_ih  = (const float*)d_in[1];  // [4H,I]
  const float* W_hh  = (const float*)d_in[2];  // [4H,H]
  const float* b_ih  = (const float*)d_in[3];  // [4H]
  const float* b_hh  = (const float*)d_in[4];  // [4H]
  const float* W_out = (const float*)d_in[5];  // [1,H]
  const float* b_out = (const float*)d_in[6];  // [1]
  float* out = (float*)d_out;                  // [B]

  char* ws = (char*)d_ws;
  __half* Whq   = (__half*)ws;  // 192*256*8 halves = 786,432 B
  float4* biasq = (float4*)(ws + (size_t)KP_ * H_ * 8 * sizeof(__half));  // 4 KB
  int*    prt   = (int*)((char*)biasq + (size_t)H_ * sizeof(float4));    // 128 KB

  hipLaunchKernelGGL(prep_scan_kernel, dim3(48 + NWIN), dim3(1024), 0, stream,
                     W_ih, W_hh, b_ih, b_hh, x, Whq, biasq, prt);
  hipLaunchKernelGGL(lstm_kernel, dim3(B_ / 2), dim3(1024), 0, stream,
                     x, (const uint4*)Whq, biasq, prt, W_out, b_out, out);
}